// Round 13
// baseline (6652.649 us; speedup 1.0000x reference)
//
#include <hip/hip_runtime.h>
#include <math.h>

#define B_    64
#define APER_ 16
#define A_    1024
#define TPAST_ 20
#define TFUT_  30
#define C_    256
#define M_    128
#define N_    256
#define H_    5
#define EMB_  16
#define D_    384
#define TTOT_ 50

typedef short bf16x8 __attribute__((ext_vector_type(8)));
typedef float f32x4 __attribute__((ext_vector_type(4)));

__device__ __forceinline__ float sigmoidf_(float x) { return 1.0f / (1.0f + expf(-x)); }
__device__ __forceinline__ float softplusf_(float x) { return (x > 20.0f) ? x : log1pf(expf(x)); }
__device__ __forceinline__ unsigned short f2bf(float f) {
    unsigned u = __float_as_uint(f);
    return (unsigned short)((u + 0x7FFFu + ((u >> 16) & 1u)) >> 16);
}
__device__ __forceinline__ float bf2f(short s) {
    return __uint_as_float(((unsigned)(unsigned short)s) << 16);
}

// ---------------------------------------------------------------------------
// Prologue kernels
// ---------------------------------------------------------------------------
struct Cvt { const float* src; short* dst; int rows, sk, dk, total; };
struct Cvt8 { Cvt c[8]; };

__global__ __launch_bounds__(256) void convert_all(Cvt8 p)
{
    const int stride = gridDim.x * 256;
    #pragma unroll
    for (int s = 0; s < 8; ++s) {
        const Cvt d = p.c[s];
        for (int idx = blockIdx.x * 256 + threadIdx.x; idx < d.total; idx += stride) {
            const int r = idx / d.dk, k = idx % d.dk;
            float v = (k < d.sk && r < d.rows) ? d.src[(size_t)r * d.sk + k] : 0.f;
            d.dst[idx] = (short)f2bf(v);
        }
    }
}

__global__ __launch_bounds__(256) void embed2_k(const float* __restrict__ past, const float* __restrict__ past_rel,
                                                const float* __restrict__ pw1, const float* __restrict__ pb1,
                                                const float* __restrict__ pw2, const float* __restrict__ pb2,
                                                const float* __restrict__ rw1, const float* __restrict__ rb1,
                                                const float* __restrict__ rw2, const float* __restrict__ rb2,
                                                short* __restrict__ emb_p, short* __restrict__ emb_r)
{
    const int idx0 = blockIdx.x * 256 + threadIdx.x;
    const int half = A_ * TPAST_;
    if (idx0 >= 2 * half) return;
    const bool second = idx0 >= half;
    const int idx = second ? idx0 - half : idx0;
    const float* x = second ? past_rel : past;
    const float* w1 = second ? rw1 : pw1; const float* b1 = second ? rb1 : pb1;
    const float* w2 = second ? rw2 : pw2; const float* b2 = second ? rb2 : pb2;
    short* emb = second ? emb_r : emb_p;

    const int a = idx / TPAST_, t = idx % TPAST_;
    const float x0 = x[(size_t)idx * 2], x1 = x[(size_t)idx * 2 + 1];
    float hbuf[8];
    #pragma unroll
    for (int j = 0; j < 8; ++j) hbuf[j] = fmaxf(0.f, w1[j * 2] * x0 + w1[j * 2 + 1] * x1 + b1[j]);
    short* e = emb + ((size_t)t * A_ + a) * EMB_;
    #pragma unroll
    for (int i = 0; i < 16; ++i) {
        float acc = b2[i];
        #pragma unroll
        for (int j = 0; j < 8; ++j) acc += w2[i * 8 + j] * hbuf[j];
        e[i] = (short)f2bf(acc);
    }
}

__global__ __launch_bounds__(256) void init_k(float* __restrict__ h, const float* __restrict__ h_bias, short* __restrict__ hb,
                                              float* __restrict__ hr, const float* __restrict__ hr_bias, short* __restrict__ hrb,
                                              const float* __restrict__ hf_bias, short* __restrict__ hfb,
                                              short* __restrict__ reads_b, const float* __restrict__ init_r,
                                              short* __restrict__ memhi, short* __restrict__ memlo,
                                              float* __restrict__ normsG, const float* __restrict__ mem_bias)
{
    const int idx = blockIdx.x * 256 + threadIdx.x;
    if (idx < B_ * N_ * M_) {
        const float v = mem_bias[idx & (N_ * M_ - 1)];
        const short hv = (short)f2bf(v);
        memhi[idx] = hv;
        memlo[idx] = (short)f2bf(v - bf2f(hv));
    }
    if (idx < B_ * N_) {
        const float* r = mem_bias + (size_t)(idx & (N_ - 1)) * M_;
        float ss = 0.f;
        for (int k = 0; k < M_; ++k) ss += r[k] * r[k];
        normsG[idx] = sqrtf(ss) + 1e-16f;
    }
    if (idx < A_ * C_) {
        float v = h_bias[idx & (C_ - 1)];
        h[idx] = v; hb[idx] = (short)f2bf(v);
        v = hr_bias[idx & (C_ - 1)];
        hr[idx] = v; hrb[idx] = (short)f2bf(v);
    }
    if (idx < H_ * A_ * D_) {
        hfb[idx] = (short)f2bf(hf_bias[idx % D_]);
    }
    if (idx < A_ * M_) reads_b[idx] = (short)f2bf(init_r[idx & (M_ - 1)]);
}

// ---------------------------------------------------------------------------
// GRU tile, role-split (round-12, proven).
// ---------------------------------------------------------------------------
__device__ __forceinline__ void gru_tile_split(
    int role, float* __restrict__ xchLane,
    const short* __restrict__ X1, int K1,
    const short* __restrict__ X2, int K2,
    const short* __restrict__ Wih, int Kpad,
    const float* __restrict__ bih,
    const short* __restrict__ Hb, const short* __restrict__ Whh,
    const float* __restrict__ bhh,
    const float* __restrict__ Hprev,
    float* __restrict__ Hnew, short* __restrict__ Hnewb,
    int G, int rowBase, int colBase, int lane)
{
    const int l16 = lane & 15;
    const int kb8 = (lane >> 4) * 8;
    const f32x4 z4 = {0.f, 0.f, 0.f, 0.f};
    f32x4 a0[2][2], a1[2][2], a2[2][2];
    #pragma unroll
    for (int i = 0; i < 2; ++i)
        #pragma unroll
        for (int j = 0; j < 2; ++j) { a0[i][j] = z4; a1[i][j] = z4; a2[i][j] = z4; }

    if (role == 0) {
        for (int kc = 0; kc < Kpad; kc += 32) {
            const int k8 = kc + kb8;
            bf16x8 ax[2];
            #pragma unroll
            for (int i = 0; i < 2; ++i) {
                const int r = rowBase + i * 16 + l16;
                bf16x8 v = {0, 0, 0, 0, 0, 0, 0, 0};
                if (k8 < K1) {
                    if (X1) v = *(const bf16x8*)(X1 + (size_t)(r & 1023) * K1 + k8);
                } else if (k8 < K1 + K2) {
                    v = *(const bf16x8*)(X2 + (size_t)r * K2 + (k8 - K1));
                }
                ax[i] = v;
            }
            #pragma unroll
            for (int j = 0; j < 2; ++j) {
                const size_t wb = (size_t)(colBase + j * 16 + l16) * Kpad + k8;
                const bf16x8 b0 = *(const bf16x8*)(Wih + wb);
                const bf16x8 b1 = *(const bf16x8*)(Wih + (size_t)G * Kpad + wb);
                const bf16x8 b2 = *(const bf16x8*)(Wih + (size_t)2 * G * Kpad + wb);
                a0[0][j] = __builtin_amdgcn_mfma_f32_16x16x32_bf16(ax[0], b0, a0[0][j], 0, 0, 0);
                a0[1][j] = __builtin_amdgcn_mfma_f32_16x16x32_bf16(ax[1], b0, a0[1][j], 0, 0, 0);
                a1[0][j] = __builtin_amdgcn_mfma_f32_16x16x32_bf16(ax[0], b1, a1[0][j], 0, 0, 0);
                a1[1][j] = __builtin_amdgcn_mfma_f32_16x16x32_bf16(ax[1], b1, a1[1][j], 0, 0, 0);
                a2[0][j] = __builtin_amdgcn_mfma_f32_16x16x32_bf16(ax[0], b2, a2[0][j], 0, 0, 0);
                a2[1][j] = __builtin_amdgcn_mfma_f32_16x16x32_bf16(ax[1], b2, a2[1][j], 0, 0, 0);
            }
        }
        #pragma unroll
        for (int i = 0; i < 2; ++i)
            #pragma unroll
            for (int j = 0; j < 2; ++j)
                #pragma unroll
                for (int q = 0; q < 4; ++q) {
                    const int base = (i * 2 + j) * 4 + q;
                    xchLane[base]      = a0[i][j][q];
                    xchLane[16 + base] = a1[i][j][q];
                    xchLane[32 + base] = a2[i][j][q];
                }
    } else {
        for (int kc = 0; kc < G; kc += 32) {
            const int k8 = kc + kb8;
            bf16x8 ah[2];
            #pragma unroll
            for (int i = 0; i < 2; ++i)
                ah[i] = *(const bf16x8*)(Hb + (size_t)(rowBase + i * 16 + l16) * G + k8);
            #pragma unroll
            for (int j = 0; j < 2; ++j) {
                const size_t wb = (size_t)(colBase + j * 16 + l16) * G + k8;
                const bf16x8 b0 = *(const bf16x8*)(Whh + wb);
                const bf16x8 b1 = *(const bf16x8*)(Whh + (size_t)G * G + wb);
                const bf16x8 b2 = *(const bf16x8*)(Whh + (size_t)2 * G * G + wb);
                a0[0][j] = __builtin_amdgcn_mfma_f32_16x16x32_bf16(ah[0], b0, a0[0][j], 0, 0, 0);
                a0[1][j] = __builtin_amdgcn_mfma_f32_16x16x32_bf16(ah[1], b0, a0[1][j], 0, 0, 0);
                a1[0][j] = __builtin_amdgcn_mfma_f32_16x16x32_bf16(ah[0], b1, a1[0][j], 0, 0, 0);
                a1[1][j] = __builtin_amdgcn_mfma_f32_16x16x32_bf16(ah[1], b1, a1[1][j], 0, 0, 0);
                a2[0][j] = __builtin_amdgcn_mfma_f32_16x16x32_bf16(ah[0], b2, a2[0][j], 0, 0, 0);
                a2[1][j] = __builtin_amdgcn_mfma_f32_16x16x32_bf16(ah[1], b2, a2[1][j], 0, 0, 0);
            }
        }
    }
    __syncthreads();
    if (role != 1) return;

    const int r4 = (lane >> 4) * 4;
    #pragma unroll
    for (int j = 0; j < 2; ++j) {
        const int col = colBase + j * 16 + l16;
        const float b0c = bih[col] + bhh[col];
        const float b1c = bih[G + col] + bhh[G + col];
        const float bi2 = bih[2 * G + col], bh2 = bhh[2 * G + col];
        #pragma unroll
        for (int i = 0; i < 2; ++i) {
            #pragma unroll
            for (int q = 0; q < 4; ++q) {
                const int row = rowBase + i * 16 + r4 + q;
                const int base = (i * 2 + j) * 4 + q;
                const float arv = a0[i][j][q] + xchLane[base];
                const float azv = a1[i][j][q] + xchLane[16 + base];
                const float aniv = xchLane[32 + base];
                const float anhv = a2[i][j][q];
                const float rr = sigmoidf_(arv + b0c);
                const float zz = sigmoidf_(azv + b1c);
                const float nn = tanhf(aniv + bi2 + rr * (anhv + bh2));
                const float hp = Hprev ? Hprev[(size_t)row * G + col]
                                       : bf2f(Hb[(size_t)row * G + col]);
                const float hv = (1.f - zz) * nn + zz * hp;
                if (Hnew) Hnew[(size_t)row * G + col] = hv;
                Hnewb[(size_t)row * G + col] = (short)f2bf(hv);
            }
        }
    }
}

__device__ __forceinline__ void gemm_tile(
    const short* __restrict__ Xb, const short* __restrict__ Wb,
    const float* __restrict__ bias, float* __restrict__ Out,
    int Ncols, int K, int rowBase, int colBase, int lane)
{
    const int l16 = lane & 15;
    const int kb8 = (lane >> 4) * 8;
    const f32x4 z4 = {0.f, 0.f, 0.f, 0.f};
    f32x4 acc[2][2] = {{z4, z4}, {z4, z4}};

    for (int kc = 0; kc < K; kc += 32) {
        const int k8 = kc + kb8;
        const bf16x8 a0 = *(const bf16x8*)(Xb + (size_t)(rowBase + l16) * K + k8);
        const bf16x8 a1 = *(const bf16x8*)(Xb + (size_t)(rowBase + 16 + l16) * K + k8);
        const bf16x8 b0 = *(const bf16x8*)(Wb + (size_t)(colBase + l16) * K + k8);
        const bf16x8 b1 = *(const bf16x8*)(Wb + (size_t)(colBase + 16 + l16) * K + k8);
        acc[0][0] = __builtin_amdgcn_mfma_f32_16x16x32_bf16(a0, b0, acc[0][0], 0, 0, 0);
        acc[0][1] = __builtin_amdgcn_mfma_f32_16x16x32_bf16(a0, b1, acc[0][1], 0, 0, 0);
        acc[1][0] = __builtin_amdgcn_mfma_f32_16x16x32_bf16(a1, b0, acc[1][0], 0, 0, 0);
        acc[1][1] = __builtin_amdgcn_mfma_f32_16x16x32_bf16(a1, b1, acc[1][1], 0, 0, 0);
    }
    const int r4 = (lane >> 4) * 4;
    #pragma unroll
    for (int j = 0; j < 2; ++j) {
        const int col = colBase + j * 16 + l16;
        if (col >= Ncols) continue;
        const float bv = bias[col];
        #pragma unroll
        for (int i = 0; i < 2; ++i)
            #pragma unroll
            for (int q = 0; q < 4; ++q) {
                const int row = rowBase + i * 16 + r4 + q;
                Out[(size_t)row * Ncols + col] = acc[i][j][q] + bv;
            }
    }
}

// ---------------------------------------------------------------------------
// phaseA: role-split GRU tiles (round-12, proven).
// ---------------------------------------------------------------------------
__global__ __launch_bounds__(256) void phaseA(
    const short* __restrict__ ep, const short* __restrict__ er,
    const short* __restrict__ enc_wih, const float* __restrict__ enc_bih,
    const short* __restrict__ enc_whh, const float* __restrict__ enc_bhh,
    const short* __restrict__ rel_wih, const float* __restrict__ rel_bih,
    const short* __restrict__ rel_whh, const float* __restrict__ rel_bhh,
    const short* __restrict__ dec_wih, const float* __restrict__ dec_bih,
    const short* __restrict__ dec_whh, const float* __restrict__ dec_bhh,
    const float* __restrict__ hc, const short* __restrict__ hbc,
    float* __restrict__ hn, short* __restrict__ hbn,
    const float* __restrict__ hrc, const short* __restrict__ hrbc,
    float* __restrict__ hrn, short* __restrict__ hrbn,
    const short* __restrict__ hfbc, short* __restrict__ hfbn,
    const short* __restrict__ reads_b,
    int decBlocks, int encBlocks)
{
    __shared__ float xch[2][64][49];
    const int bid = blockIdx.x;
    const int wv = threadIdx.x >> 6;
    const int lane = threadIdx.x & 63;
    const int pair = wv >> 1, role = wv & 1;
    float* xchLane = &xch[pair][lane][0];

    if (bid < decBlocks) {
        const int tile = bid * 2 + pair;
        gru_tile_split(role, xchLane,
                       hbc, 256, reads_b, 128, dec_wih, 384, dec_bih,
                       hfbc, dec_whh, dec_bhh, nullptr, nullptr, hfbn, D_,
                       (tile / 12) * 32, (tile % 12) * 32, lane);
    } else if (bid < decBlocks + encBlocks) {
        const int tile = (bid - decBlocks) * 2 + pair;
        gru_tile_split(role, xchLane,
                       ep, 16, reads_b, 128, enc_wih, 160, enc_bih,
                       hbc, enc_whh, enc_bhh, hc, hn, hbn, C_,
                       (tile >> 3) * 32, (tile & 7) * 32, lane);
    } else {
        const int tile = (bid - decBlocks - encBlocks) * 2 + pair;
        gru_tile_split(role, xchLane,
                       er, 16, nullptr, 0, rel_wih, 32, rel_bih,
                       hrbc, rel_whh, rel_bhh, hrc, hrn, hrbn, C_,
                       (tile >> 3) * 32, (tile & 7) * 32, lane);
    }
}

// ---------------------------------------------------------------------------
// phaseB: [per-scene fused wp-GEMM + NTM write] | rp GEMM | out(t-1).
// Write blocks: bid < wrBlocks (64). All depend only on phaseA outputs.
// ---------------------------------------------------------------------------
__global__ __launch_bounds__(256) void phaseB(
    const short* __restrict__ hbn, const short* __restrict__ write_w_b,
    const float* __restrict__ write_b,
    short* __restrict__ memhi, short* __restrict__ memlo,
    float* __restrict__ normsG,
    const short* __restrict__ hrbn, const short* __restrict__ read_w_b,
    const float* __restrict__ read_b, float* __restrict__ rp,
    const short* __restrict__ hfbn, const float* __restrict__ out_w,
    const float* __restrict__ out_b, float* __restrict__ predrel,
    int outT, int wrBlocks, int rpBlocks)
{
    __shared__ float wpL[16][420];
    __shared__ float kwL[16][132], erL[16][132], adL[16][132];
    __shared__ float betaL[16];
    const int bid = blockIdx.x;
    const int tid = threadIdx.x;
    const int wave = tid >> 6;
    const int lane = tid & 63;

    if (bid < wrBlocks) {
        const int b = bid;
        const int l16 = lane & 15;
        const int kb8 = (lane >> 4) * 8;
        const f32x4 z4 = {0.f, 0.f, 0.f, 0.f};

        // wp GEMM: 13 col-tiles of 32 over 16 agent rows, K=256
        #pragma unroll
        for (int ti = 0; ti < 4; ++ti) {
            const int tile = wave * 4 + ti;
            if (tile >= 13) break;
            const int colBase = tile * 32;
            f32x4 acc[2] = {z4, z4};
            for (int kc = 0; kc < 256; kc += 32) {
                const int k8 = kc + kb8;
                const bf16x8 av = *(const bf16x8*)(hbn + (size_t)(b * 16 + l16) * C_ + k8);
                const bf16x8 b0 = *(const bf16x8*)(write_w_b + (size_t)(colBase + l16) * C_ + k8);
                const bf16x8 b1 = *(const bf16x8*)(write_w_b + (size_t)(colBase + 16 + l16) * C_ + k8);
                acc[0] = __builtin_amdgcn_mfma_f32_16x16x32_bf16(av, b0, acc[0], 0, 0, 0);
                acc[1] = __builtin_amdgcn_mfma_f32_16x16x32_bf16(av, b1, acc[1], 0, 0, 0);
            }
            const int r4 = (lane >> 4) * 4;
            #pragma unroll
            for (int j = 0; j < 2; ++j) {
                const int col = colBase + j * 16 + l16;
                if (col >= 385) continue;
                #pragma unroll
                for (int q = 0; q < 4; ++q)
                    wpL[r4 + q][col] = acc[j][q] + write_b[col];
            }
        }
        __syncthreads();

        // precompute kw / er / ad / beta
        for (int idx = tid; idx < 2048; idx += 256) {
            const int a2 = idx >> 7, k = idx & 127;
            kwL[a2][k] = tanhf(wpL[a2][k]);
            erL[a2][k] = sigmoidf_(wpL[a2][129 + k]);
            adL[a2][k] = tanhf(wpL[a2][257 + k]);
        }
        if (tid < 16) betaL[tid] = softplusf_(wpL[tid][128]);
        __syncthreads();

        const int a = tid >> 4, s = tid & 15;
        // key norm (16-lane group reduce)
        float kss = 0.f;
        #pragma unroll
        for (int i = 0; i < 8; ++i) { const float v = kwL[a][s * 8 + i]; kss += v * v; }
        #pragma unroll
        for (int m = 1; m < 16; m <<= 1) kss += __shfl_xor(kss, m);
        const float knorm = sqrtf(kss) + 1e-16f;

        // cosine sim for slot s of agent a's band
        const size_t row = (size_t)(b * N_) + a * 16 + s;
        const short* hi = memhi + row * M_;
        const short* lo = memlo + row * M_;
        float dot = 0.f, ss = 0.f;
        for (int k8 = 0; k8 < 128; k8 += 8) {
            const bf16x8 vh = *(const bf16x8*)(hi + k8);
            const bf16x8 vl = *(const bf16x8*)(lo + k8);
            #pragma unroll
            for (int r = 0; r < 8; ++r) {
                const float v = bf2f(vh[r]) + bf2f(vl[r]);
                dot = fmaf(kwL[a][k8 + r], v, dot);
                ss = fmaf(v, v, ss);
            }
        }
        const float logit = betaL[a] * (dot / ((sqrtf(ss) + 1e-16f) * knorm));
        float mx = logit;
        #pragma unroll
        for (int m = 1; m < 16; m <<= 1) mx = fmaxf(mx, __shfl_xor(mx, m));
        const float e = __expf(logit - mx);
        float sum = e;
        #pragma unroll
        for (int m = 1; m < 16; m <<= 1) sum += __shfl_xor(sum, m);
        const float ww = e / sum;

        // erase/add update of this slot row; per-slot norm
        float ssq = 0.f;
        short* hiw = memhi + row * M_;
        short* low = memlo + row * M_;
        for (int k8 = 0; k8 < 128; k8 += 8) {
            const bf16x8 vh = *(const bf16x8*)(hi + k8);
            const bf16x8 vl = *(const bf16x8*)(lo + k8);
            bf16x8 oh, ol;
            #pragma unroll
            for (int r = 0; r < 8; ++r) {
                const float old = bf2f(vh[r]) + bf2f(vl[r]);
                const float v = old * (1.f - ww * erL[a][k8 + r]) + ww * adL[a][k8 + r];
                const short hv = (short)f2bf(v);
                oh[r] = hv;
                ol[r] = (short)f2bf(v - bf2f(hv));
                ssq = fmaf(v, v, ssq);
            }
            *(bf16x8*)(hiw + k8) = oh;
            *(bf16x8*)(low + k8) = ol;
        }
        normsG[row] = sqrtf(ssq) + 1e-16f;
    } else if (bid < wrBlocks + rpBlocks) {
        const int tile = (bid - wrBlocks) * 4 + wave;     // 672: 32 rowT x 21 colT
        gemm_tile(hrbn, read_w_b, read_b, rp, 645, C_,
                  (tile & 31) * 32, (tile >> 5) * 32, lane);
    } else {
        const int widx = (bid - wrBlocks - rpBlocks) * 4 + wave;
        const int g = lane >> 3, li = lane & 7;
        const int row = widx * 8 + g;                     // < 5120
        const short* hrow = hfbn + (size_t)row * D_;
        float a0 = 0.f, a1 = 0.f;
        #pragma unroll
        for (int u = 0; u < 6; ++u) {
            const int k0 = u * 64 + li * 8;
            const bf16x8 v = *(const bf16x8*)(hrow + k0);
            #pragma unroll
            for (int r = 0; r < 8; ++r) {
                const float f = bf2f(v[r]);
                a0 = fmaf(f, out_w[k0 + r], a0);
                a1 = fmaf(f, out_w[D_ + k0 + r], a1);
            }
        }
        a0 += __shfl_xor(a0, 1); a0 += __shfl_xor(a0, 2); a0 += __shfl_xor(a0, 4);
        a1 += __shfl_xor(a1, 1); a1 += __shfl_xor(a1, 2); a1 += __shfl_xor(a1, 4);
        if (li == 0) {
            const int hh = row >> 10, aa = row & 1023;
            float* o = predrel + (((size_t)aa * H_ + hh) * TFUT_ + outT) * 2;
            o[0] = a0 + out_b[0];
            o[1] = a1 + out_b[1];
        }
    }
}

// ---------------------------------------------------------------------------
// NTM read (sims from hi/lo; PV reconstructs hi+lo)
// ---------------------------------------------------------------------------
__global__ __launch_bounds__(256) void read_k2(const float* __restrict__ rp,
                                               const short* __restrict__ memhi,
                                               const short* __restrict__ memlo,
                                               const float* __restrict__ normsG,
                                               short* __restrict__ reads_b)
{
    const int b = blockIdx.x;
    const int h = blockIdx.y;
    __shared__ __align__(16) float kq[16 * 132];
    __shared__ float S[16 * 260];
    __shared__ float beta_s[16], knorm_s[16], inv_s[16];
    const int t = threadIdx.x;
    const int a = t >> 4;
    const int sub = t & 15;

    {
        const float* base = rp + ((size_t)(b * 16 + a)) * 645 + h * 129;
        const int k0 = sub * 8;
        float v[8]; float ss = 0.f;
        #pragma unroll
        for (int r = 0; r < 8; ++r) { v[r] = tanhf(base[k0 + r]); ss += v[r] * v[r]; }
        float* dst = kq + a * 132 + k0;
        *(float4*)dst = make_float4(v[0], v[1], v[2], v[3]);
        *(float4*)(dst + 4) = make_float4(v[4], v[5], v[6], v[7]);
        #pragma unroll
        for (int m = 1; m < 16; m <<= 1) ss += __shfl_xor(ss, m);
        if (sub == 0) {
            knorm_s[a] = sqrtf(ss) + 1e-16f;
            beta_s[a] = softplusf_(base[128]);
        }
    }
    __syncthreads();

    {
        const int wave = t >> 6, lane = t & 63;
        const int l16 = lane & 15, kb8 = (lane >> 4) * 8;
        const int slotBase = wave * 64;
        const f32x4 z4 = {0.f, 0.f, 0.f, 0.f};
        f32x4 acc[4] = {z4, z4, z4, z4};
        const short* mbh = memhi + (size_t)b * N_ * M_;
        const short* mbl = memlo + (size_t)b * N_ * M_;
        #pragma unroll
        for (int kc = 0; kc < 128; kc += 32) {
            const float* ap = kq + l16 * 132 + kc + kb8;
            bf16x8 ah, al;
            #pragma unroll
            for (int r = 0; r < 8; ++r) {
                const float av = ap[r];
                const short hv = (short)f2bf(av);
                ah[r] = hv; al[r] = (short)f2bf(av - bf2f(hv));
            }
            #pragma unroll
            for (int tt = 0; tt < 4; ++tt) {
                const size_t roff = (size_t)(slotBase + tt * 16 + l16) * M_ + kc + kb8;
                const bf16x8 bh = *(const bf16x8*)(mbh + roff);
                const bf16x8 bl = *(const bf16x8*)(mbl + roff);
                acc[tt] = __builtin_amdgcn_mfma_f32_16x16x32_bf16(ah, bh, acc[tt], 0, 0, 0);
                acc[tt] = __builtin_amdgcn_mfma_f32_16x16x32_bf16(ah, bl, acc[tt], 0, 0, 0);
                acc[tt] = __builtin_amdgcn_mfma_f32_16x16x32_bf16(al, bh, acc[tt], 0, 0, 0);
            }
        }
        const int r4 = (lane >> 4) * 4;
        #pragma unroll
        for (int tt = 0; tt < 4; ++tt) {
            const int slot = slotBase + tt * 16 + l16;
            const float nv = normsG[b * N_ + slot];
            #pragma unroll
            for (int q = 0; q < 4; ++q) {
                const int aq = r4 + q;
                const float lg = ((slot >> 4) == aq) ? -1e30f
                               : beta_s[aq] * acc[tt][q] / (nv * knorm_s[aq]);
                S[aq * 260 + slot] = lg;
            }
        }
    }
    __syncthreads();

    {
        float mx = -1e30f;
        #pragma unroll
        for (int i = 0; i < 16; ++i) mx = fmaxf(mx, S[a * 260 + sub + 16 * i]);
        #pragma unroll
        for (int m = 1; m < 16; m <<= 1) mx = fmaxf(mx, __shfl_xor(mx, m));
        float e[16]; float sum = 0.f;
        #pragma unroll
        for (int i = 0; i < 16; ++i) { e[i] = __expf(S[a * 260 + sub + 16 * i] - mx); sum += e[i]; }
        #pragma unroll
        for (int i = 0; i < 16; ++i) S[a * 260 + sub + 16 * i] = e[i];
        #pragma unroll
        for (int m = 1; m < 16; m <<= 1) sum += __shfl_xor(sum, m);
        if (sub == 0) inv_s[a] = 1.f / sum;
    }
    __syncthreads();

    {
        const int m0 = sub * 8;
        const short* mbh = memhi + (size_t)b * N_ * M_ + m0;
        const short* mbl = memlo + (size_t)b * N_ * M_ + m0;
        float acc[8];
        #pragma unroll
        for (int r = 0; r < 8; ++r) acc[r] = 0.f;
        const float* Sa = S + a * 260;
        #pragma unroll 2
        for (int n = 0; n < N_; ++n) {
            const float w = Sa[n];
            const bf16x8 vh = *(const bf16x8*)(mbh + (size_t)n * M_);
            const bf16x8 vl = *(const bf16x8*)(mbl + (size_t)n * M_);
            #pragma unroll
            for (int r = 0; r < 8; ++r)
                acc[r] = fmaf(w, bf2f(vh[r]) + bf2f(vl[r]), acc[r]);
        }
        const float inv = inv_s[a];
        short pk[8];
        #pragma unroll
        for (int r = 0; r < 8; ++r) pk[r] = (short)f2bf(acc[r] * inv);
        *(bf16x8*)(reads_b + ((size_t)h * A_ + b * 16 + a) * M_ + m0) = *(bf16x8*)pk;
    }
}

__global__ __launch_bounds__(256) void cumsum_k(const float* __restrict__ past,
                                                const float* __restrict__ predrel,
                                                float* __restrict__ pred)
{
    const int idx = blockIdx.x * 256 + threadIdx.x;
    if (idx >= A_ * H_ * 2) return;
    const int c = idx & 1;
    const int ah = idx >> 1;
    const int a = ah / H_;
    float acc = past[((size_t)a * TPAST_ + TPAST_ - 1) * 2 + c];
    const float* pr = predrel + (size_t)ah * TFUT_ * 2 + c;
    float* pd = pred + (size_t)ah * TFUT_ * 2 + c;
    for (int t = 0; t < TFUT_; ++t) { acc += pr[t * 2]; pd[t * 2] = acc; }
}

extern "C" void kernel_launch(void* const* d_in, const int* in_sizes, int n_in,
                              void* d_out, int out_size, void* d_ws, size_t ws_size,
                              hipStream_t stream)
{
    const float* past       = (const float*)d_in[0];
    const float* past_rel   = (const float*)d_in[1];
    const float* ep_w1      = (const float*)d_in[2];
    const float* ep_b1      = (const float*)d_in[3];
    const float* ep_w2      = (const float*)d_in[4];
    const float* ep_b2      = (const float*)d_in[5];
    const float* er_w1      = (const float*)d_in[6];
    const float* er_b1      = (const float*)d_in[7];
    const float* er_w2      = (const float*)d_in[8];
    const float* er_b2      = (const float*)d_in[9];
    const float* enc_wih    = (const float*)d_in[10];
    const float* enc_whh    = (const float*)d_in[11];
    const float* enc_bih    = (const float*)d_in[12];
    const float* enc_bhh    = (const float*)d_in[13];
    const float* rel_wih    = (const float*)d_in[14];
    const float* rel_whh    = (const float*)d_in[15];
    const float* rel_bih    = (const float*)d_in[16];
    const float* rel_bhh    = (const float*)d_in[17];
    const float* dec_wih    = (const float*)d_in[18];
    const float* dec_whh    = (const float*)d_in[19];
    const float* dec_bih    = (const float*)d_in[20];
    const float* dec_bhh    = (const float*)d_in[21];
    const float* out_w      = (const float*)d_in[22];
    const float* out_b      = (const float*)d_in[23];
    const float* read_w     = (const float*)d_in[24];
    const float* read_b     = (const float*)d_in[25];
    const float* write_w    = (const float*)d_in[26];
    const float* write_b    = (const float*)d_in[27];
    const float* init_r     = (const float*)d_in[28];
    const float* h_bias     = (const float*)d_in[29];
    const float* h_rel_bias = (const float*)d_in[30];
    const float* h_fut_bias = (const float*)d_in[31];
    const float* mem_bias   = (const float*)d_in[32];

    float* pred    = (float*)d_out;
    float* predrel = pred + (size_t)A_ * H_ * TFUT_ * 2;

    float* ws = (float*)d_ws;
    size_t off = 0;
    auto alloc = [&](size_t n) { float* p = ws + off; off += n; return p; };
    float* h0     = alloc((size_t)A_ * C_);
    float* h1     = alloc((size_t)A_ * C_);
    float* hr0    = alloc((size_t)A_ * C_);
    float* hr1    = alloc((size_t)A_ * C_);
    float* rp     = alloc((size_t)A_ * 645);
    float* normsG = alloc((size_t)B_ * N_);

    short* sws = (short*)(ws + off);
    size_t soff = 0;
    auto salloc = [&](size_t n) { short* p = sws + soff; soff += n; return p; };
    short* emb_p_b   = salloc((size_t)TPAST_ * A_ * EMB_);
    short* emb_r_b   = salloc((size_t)TPAST_ * A_ * EMB_);
    short* hb0       = salloc((size_t)A_ * C_);
    short* hb1       = salloc((size_t)A_ * C_);
    short* hrb0      = salloc((size_t)A_ * C_);
    short* hrb1      = salloc((size_t)A_ * C_);
    short* hfb0      = salloc((size_t)H_ * A_ * D_);
    short* hfb1      = salloc((size_t)H_ * A_ * D_);
    short* reads_b   = salloc((size_t)H_ * A_ * M_);
    short* memhi     = salloc((size_t)B_ * N_ * M_);
    short* memlo     = salloc((size_t)B_ * N_ * M_);
    short* enc_wih_b = salloc((size_t)768 * 160);
    short* enc_whh_b = salloc((size_t)768 * 256);
    short* rel_wih_b = salloc((size_t)768 * 32);
    short* rel_whh_b = salloc((size_t)768 * 256);
    short* dec_wih_b = salloc((size_t)1152 * 384);
    short* dec_whh_b = salloc((size_t)1152 * 384);
    short* write_w_b = salloc((size_t)416 * 256);
    short* read_w_b  = salloc((size_t)672 * 256);
    (void)ws_size; (void)in_sizes; (void)n_in; (void)out_size;

    Cvt8 cp;
    cp.c[0] = {enc_wih, enc_wih_b, 768, 144, 160, 768 * 160};
    cp.c[1] = {enc_whh, enc_whh_b, 768, 256, 256, 768 * 256};
    cp.c[2] = {rel_wih, rel_wih_b, 768, 16, 32, 768 * 32};
    cp.c[3] = {rel_whh, rel_whh_b, 768, 256, 256, 768 * 256};
    cp.c[4] = {dec_wih, dec_wih_b, 1152, 384, 384, 1152 * 384};
    cp.c[5] = {dec_whh, dec_whh_b, 1152, 384, 384, 1152 * 384};
    cp.c[6] = {write_w, write_w_b, 385, 256, 256, 416 * 256};
    cp.c[7] = {read_w, read_w_b, 645, 256, 256, 672 * 256};
    convert_all<<<1024, 256, 0, stream>>>(cp);

    init_k<<<(B_ * N_ * M_ + 255) / 256, 256, 0, stream>>>(
        h0, h_bias, hb0, hr0, h_rel_bias, hrb0, h_fut_bias, hfb0,
        reads_b, init_r, memhi, memlo, normsG, mem_bias);
    embed2_k<<<(2 * A_ * TPAST_ + 255) / 256, 256, 0, stream>>>(
        past, past_rel, ep_w1, ep_b1, ep_w2, ep_b2, er_w1, er_b1, er_w2, er_b2,
        emb_p_b, emb_r_b);

    float *hc = h0, *hn = h1, *hrc = hr0, *hrn = hr1;
    short *hbc = hb0, *hbn = hb1, *hrbc = hrb0, *hrbn = hrb1, *hfbc = hfb0, *hfbn = hfb1;

    const dim3 g_read(B_, H_);   // (64, 5)

    for (int t = 0; t < TTOT_; ++t) {
        const short* ep = (t < TPAST_) ? emb_p_b + (size_t)t * A_ * EMB_ : nullptr;
        const short* er = (t < TPAST_) ? emb_r_b + (size_t)t * A_ * EMB_ : nullptr;

        // phase A: dec(t-1) [t>=1] + enc(t) + rel(t)
        const int decBlocks = (t == 0) ? 0 : 960;
        phaseA<<<decBlocks + 256, 256, 0, stream>>>(
            ep, er,
            enc_wih_b, enc_bih, enc_whh_b, enc_bhh,
            rel_wih_b, rel_bih, rel_whh_b, rel_bhh,
            dec_wih_b, dec_bih, dec_whh_b, dec_bhh,
            hc, hbc, hn, hbn,
            hrc, hrbc, hrn, hrbn,
            hfbc, hfbn,
            reads_b, decBlocks, 128);

        // phase B: write-fused (64) + rp GEMM (168) + out(t-1) (160 when t>=21)
        const int gridB = (t >= 21) ? 392 : 232;
        phaseB<<<gridB, 256, 0, stream>>>(
            hbn, write_w_b, write_b, memhi, memlo, normsG,
            hrbn, read_w_b, read_b, rp,
            hfbn, out_w, out_b, predrel, t - 21, 64, 168);

        // memory read -> reads_b(t)
        read_k2<<<g_read, 256, 0, stream>>>(rp, memhi, memlo, normsG, reads_b);

        // swaps
        float* tf; short* ts;
        tf = hc; hc = hn; hn = tf;       ts = hbc; hbc = hbn; hbn = ts;
        tf = hrc; hrc = hrn; hrn = tf;   ts = hrbc; hrbc = hrbn; hrbn = ts;
        if (t >= 1) {
            ts = hfbc; hfbc = hfbn; hfbn = ts;
        }
    }

    // epilogue: dec(49), out(49), cumsum
    phaseA<<<960, 256, 0, stream>>>(
        nullptr, nullptr,
        enc_wih_b, enc_bih, enc_whh_b, enc_bhh,
        rel_wih_b, rel_bih, rel_whh_b, rel_bhh,
        dec_wih_b, dec_bih, dec_whh_b, dec_bhh,
        hc, hbc, hn, hbn,
        hrc, hrbc, hrn, hrbn,
        hfbc, hfbn,
        reads_b, 960, 0);
    phaseB<<<160, 256, 0, stream>>>(
        hbn, write_w_b, write_b, memhi, memlo, normsG,
        hrbn, read_w_b, read_b, rp,
        hfbn, out_w, out_b, predrel, TFUT_ - 1, 0, 0);
    cumsum_k<<<(A_ * H_ * 2 + 255) / 256, 256, 0, stream>>>(past, predrel, pred);
}

// Round 14
// 6019.401 us; speedup vs baseline: 1.1052x; 1.1052x over previous
//
#include <hip/hip_runtime.h>
#include <math.h>

#define B_    64
#define APER_ 16
#define A_    1024
#define TPAST_ 20
#define TFUT_  30
#define C_    256
#define M_    128
#define N_    256
#define H_    5
#define EMB_  16
#define D_    384
#define TTOT_ 50

typedef short bf16x8 __attribute__((ext_vector_type(8)));
typedef float f32x4 __attribute__((ext_vector_type(4)));

__device__ __forceinline__ float sigmoidf_(float x) { return 1.0f / (1.0f + expf(-x)); }
__device__ __forceinline__ float softplusf_(float x) { return (x > 20.0f) ? x : log1pf(expf(x)); }
__device__ __forceinline__ unsigned short f2bf(float f) {
    unsigned u = __float_as_uint(f);
    return (unsigned short)((u + 0x7FFFu + ((u >> 16) & 1u)) >> 16);
}
__device__ __forceinline__ float bf2f(short s) {
    return __uint_as_float(((unsigned)(unsigned short)s) << 16);
}

// ---------------------------------------------------------------------------
// Prologue kernels
// ---------------------------------------------------------------------------
struct Cvt { const float* src; short* dst; int rows, sk, dk, total; };
struct Cvt8 { Cvt c[8]; };

__global__ __launch_bounds__(256) void convert_all(Cvt8 p)
{
    const int stride = gridDim.x * 256;
    #pragma unroll
    for (int s = 0; s < 8; ++s) {
        const Cvt d = p.c[s];
        for (int idx = blockIdx.x * 256 + threadIdx.x; idx < d.total; idx += stride) {
            const int r = idx / d.dk, k = idx % d.dk;
            float v = (k < d.sk && r < d.rows) ? d.src[(size_t)r * d.sk + k] : 0.f;
            d.dst[idx] = (short)f2bf(v);
        }
    }
}

__global__ __launch_bounds__(256) void embed2_k(const float* __restrict__ past, const float* __restrict__ past_rel,
                                                const float* __restrict__ pw1, const float* __restrict__ pb1,
                                                const float* __restrict__ pw2, const float* __restrict__ pb2,
                                                const float* __restrict__ rw1, const float* __restrict__ rb1,
                                                const float* __restrict__ rw2, const float* __restrict__ rb2,
                                                short* __restrict__ emb_p, short* __restrict__ emb_r)
{
    const int idx0 = blockIdx.x * 256 + threadIdx.x;
    const int half = A_ * TPAST_;
    if (idx0 >= 2 * half) return;
    const bool second = idx0 >= half;
    const int idx = second ? idx0 - half : idx0;
    const float* x = second ? past_rel : past;
    const float* w1 = second ? rw1 : pw1; const float* b1 = second ? rb1 : pb1;
    const float* w2 = second ? rw2 : pw2; const float* b2 = second ? rb2 : pb2;
    short* emb = second ? emb_r : emb_p;

    const int a = idx / TPAST_, t = idx % TPAST_;
    const float x0 = x[(size_t)idx * 2], x1 = x[(size_t)idx * 2 + 1];
    float hbuf[8];
    #pragma unroll
    for (int j = 0; j < 8; ++j) hbuf[j] = fmaxf(0.f, w1[j * 2] * x0 + w1[j * 2 + 1] * x1 + b1[j]);
    short* e = emb + ((size_t)t * A_ + a) * EMB_;
    #pragma unroll
    for (int i = 0; i < 16; ++i) {
        float acc = b2[i];
        #pragma unroll
        for (int j = 0; j < 8; ++j) acc += w2[i * 8 + j] * hbuf[j];
        e[i] = (short)f2bf(acc);
    }
}

__global__ __launch_bounds__(256) void init_k(float* __restrict__ h, const float* __restrict__ h_bias, short* __restrict__ hb,
                                              float* __restrict__ hr, const float* __restrict__ hr_bias, short* __restrict__ hrb,
                                              const float* __restrict__ hf_bias, short* __restrict__ hfb,
                                              short* __restrict__ reads_b, const float* __restrict__ init_r,
                                              short* __restrict__ memhi, short* __restrict__ memlo,
                                              float* __restrict__ normsG, const float* __restrict__ mem_bias)
{
    const int idx = blockIdx.x * 256 + threadIdx.x;
    if (idx < B_ * N_ * M_) {
        const float v = mem_bias[idx & (N_ * M_ - 1)];
        const short hv = (short)f2bf(v);
        memhi[idx] = hv;
        memlo[idx] = (short)f2bf(v - bf2f(hv));
    }
    if (idx < B_ * N_) {
        const float* r = mem_bias + (size_t)(idx & (N_ - 1)) * M_;
        float ss = 0.f;
        for (int k = 0; k < M_; ++k) ss += r[k] * r[k];
        normsG[idx] = sqrtf(ss) + 1e-16f;
    }
    if (idx < A_ * C_) {
        float v = h_bias[idx & (C_ - 1)];
        h[idx] = v; hb[idx] = (short)f2bf(v);
        v = hr_bias[idx & (C_ - 1)];
        hr[idx] = v; hrb[idx] = (short)f2bf(v);
    }
    if (idx < H_ * A_ * D_) {
        hfb[idx] = (short)f2bf(hf_bias[idx % D_]);
    }
    if (idx < A_ * M_) reads_b[idx] = (short)f2bf(init_r[idx & (M_ - 1)]);
}

// ---------------------------------------------------------------------------
// GRU tile, role-split (round-12, proven).
// ---------------------------------------------------------------------------
__device__ __forceinline__ void gru_tile_split(
    int role, float* __restrict__ xchLane,
    const short* __restrict__ X1, int K1,
    const short* __restrict__ X2, int K2,
    const short* __restrict__ Wih, int Kpad,
    const float* __restrict__ bih,
    const short* __restrict__ Hb, const short* __restrict__ Whh,
    const float* __restrict__ bhh,
    const float* __restrict__ Hprev,
    float* __restrict__ Hnew, short* __restrict__ Hnewb,
    int G, int rowBase, int colBase, int lane)
{
    const int l16 = lane & 15;
    const int kb8 = (lane >> 4) * 8;
    const f32x4 z4 = {0.f, 0.f, 0.f, 0.f};
    f32x4 a0[2][2], a1[2][2], a2[2][2];
    #pragma unroll
    for (int i = 0; i < 2; ++i)
        #pragma unroll
        for (int j = 0; j < 2; ++j) { a0[i][j] = z4; a1[i][j] = z4; a2[i][j] = z4; }

    if (role == 0) {
        for (int kc = 0; kc < Kpad; kc += 32) {
            const int k8 = kc + kb8;
            bf16x8 ax[2];
            #pragma unroll
            for (int i = 0; i < 2; ++i) {
                const int r = rowBase + i * 16 + l16;
                bf16x8 v = {0, 0, 0, 0, 0, 0, 0, 0};
                if (k8 < K1) {
                    if (X1) v = *(const bf16x8*)(X1 + (size_t)(r & 1023) * K1 + k8);
                } else if (k8 < K1 + K2) {
                    v = *(const bf16x8*)(X2 + (size_t)r * K2 + (k8 - K1));
                }
                ax[i] = v;
            }
            #pragma unroll
            for (int j = 0; j < 2; ++j) {
                const size_t wb = (size_t)(colBase + j * 16 + l16) * Kpad + k8;
                const bf16x8 b0 = *(const bf16x8*)(Wih + wb);
                const bf16x8 b1 = *(const bf16x8*)(Wih + (size_t)G * Kpad + wb);
                const bf16x8 b2 = *(const bf16x8*)(Wih + (size_t)2 * G * Kpad + wb);
                a0[0][j] = __builtin_amdgcn_mfma_f32_16x16x32_bf16(ax[0], b0, a0[0][j], 0, 0, 0);
                a0[1][j] = __builtin_amdgcn_mfma_f32_16x16x32_bf16(ax[1], b0, a0[1][j], 0, 0, 0);
                a1[0][j] = __builtin_amdgcn_mfma_f32_16x16x32_bf16(ax[0], b1, a1[0][j], 0, 0, 0);
                a1[1][j] = __builtin_amdgcn_mfma_f32_16x16x32_bf16(ax[1], b1, a1[1][j], 0, 0, 0);
                a2[0][j] = __builtin_amdgcn_mfma_f32_16x16x32_bf16(ax[0], b2, a2[0][j], 0, 0, 0);
                a2[1][j] = __builtin_amdgcn_mfma_f32_16x16x32_bf16(ax[1], b2, a2[1][j], 0, 0, 0);
            }
        }
        #pragma unroll
        for (int i = 0; i < 2; ++i)
            #pragma unroll
            for (int j = 0; j < 2; ++j)
                #pragma unroll
                for (int q = 0; q < 4; ++q) {
                    const int base = (i * 2 + j) * 4 + q;
                    xchLane[base]      = a0[i][j][q];
                    xchLane[16 + base] = a1[i][j][q];
                    xchLane[32 + base] = a2[i][j][q];
                }
    } else {
        for (int kc = 0; kc < G; kc += 32) {
            const int k8 = kc + kb8;
            bf16x8 ah[2];
            #pragma unroll
            for (int i = 0; i < 2; ++i)
                ah[i] = *(const bf16x8*)(Hb + (size_t)(rowBase + i * 16 + l16) * G + k8);
            #pragma unroll
            for (int j = 0; j < 2; ++j) {
                const size_t wb = (size_t)(colBase + j * 16 + l16) * G + k8;
                const bf16x8 b0 = *(const bf16x8*)(Whh + wb);
                const bf16x8 b1 = *(const bf16x8*)(Whh + (size_t)G * G + wb);
                const bf16x8 b2 = *(const bf16x8*)(Whh + (size_t)2 * G * G + wb);
                a0[0][j] = __builtin_amdgcn_mfma_f32_16x16x32_bf16(ah[0], b0, a0[0][j], 0, 0, 0);
                a0[1][j] = __builtin_amdgcn_mfma_f32_16x16x32_bf16(ah[1], b0, a0[1][j], 0, 0, 0);
                a1[0][j] = __builtin_amdgcn_mfma_f32_16x16x32_bf16(ah[0], b1, a1[0][j], 0, 0, 0);
                a1[1][j] = __builtin_amdgcn_mfma_f32_16x16x32_bf16(ah[1], b1, a1[1][j], 0, 0, 0);
                a2[0][j] = __builtin_amdgcn_mfma_f32_16x16x32_bf16(ah[0], b2, a2[0][j], 0, 0, 0);
                a2[1][j] = __builtin_amdgcn_mfma_f32_16x16x32_bf16(ah[1], b2, a2[1][j], 0, 0, 0);
            }
        }
    }
    __syncthreads();
    if (role != 1) return;

    const int r4 = (lane >> 4) * 4;
    #pragma unroll
    for (int j = 0; j < 2; ++j) {
        const int col = colBase + j * 16 + l16;
        const float b0c = bih[col] + bhh[col];
        const float b1c = bih[G + col] + bhh[G + col];
        const float bi2 = bih[2 * G + col], bh2 = bhh[2 * G + col];
        #pragma unroll
        for (int i = 0; i < 2; ++i) {
            #pragma unroll
            for (int q = 0; q < 4; ++q) {
                const int row = rowBase + i * 16 + r4 + q;
                const int base = (i * 2 + j) * 4 + q;
                const float arv = a0[i][j][q] + xchLane[base];
                const float azv = a1[i][j][q] + xchLane[16 + base];
                const float aniv = xchLane[32 + base];
                const float anhv = a2[i][j][q];
                const float rr = sigmoidf_(arv + b0c);
                const float zz = sigmoidf_(azv + b1c);
                const float nn = tanhf(aniv + bi2 + rr * (anhv + bh2));
                const float hp = Hprev ? Hprev[(size_t)row * G + col]
                                       : bf2f(Hb[(size_t)row * G + col]);
                const float hv = (1.f - zz) * nn + zz * hp;
                if (Hnew) Hnew[(size_t)row * G + col] = hv;
                Hnewb[(size_t)row * G + col] = (short)f2bf(hv);
            }
        }
    }
}

__device__ __forceinline__ void gemm_tile(
    const short* __restrict__ Xb, const short* __restrict__ Wb,
    const float* __restrict__ bias, float* __restrict__ Out,
    int Ncols, int K, int rowBase, int colBase, int lane)
{
    const int l16 = lane & 15;
    const int kb8 = (lane >> 4) * 8;
    const f32x4 z4 = {0.f, 0.f, 0.f, 0.f};
    f32x4 acc[2][2] = {{z4, z4}, {z4, z4}};

    for (int kc = 0; kc < K; kc += 32) {
        const int k8 = kc + kb8;
        const bf16x8 a0 = *(const bf16x8*)(Xb + (size_t)(rowBase + l16) * K + k8);
        const bf16x8 a1 = *(const bf16x8*)(Xb + (size_t)(rowBase + 16 + l16) * K + k8);
        const bf16x8 b0 = *(const bf16x8*)(Wb + (size_t)(colBase + l16) * K + k8);
        const bf16x8 b1 = *(const bf16x8*)(Wb + (size_t)(colBase + 16 + l16) * K + k8);
        acc[0][0] = __builtin_amdgcn_mfma_f32_16x16x32_bf16(a0, b0, acc[0][0], 0, 0, 0);
        acc[0][1] = __builtin_amdgcn_mfma_f32_16x16x32_bf16(a0, b1, acc[0][1], 0, 0, 0);
        acc[1][0] = __builtin_amdgcn_mfma_f32_16x16x32_bf16(a1, b0, acc[1][0], 0, 0, 0);
        acc[1][1] = __builtin_amdgcn_mfma_f32_16x16x32_bf16(a1, b1, acc[1][1], 0, 0, 0);
    }
    const int r4 = (lane >> 4) * 4;
    #pragma unroll
    for (int j = 0; j < 2; ++j) {
        const int col = colBase + j * 16 + l16;
        if (col >= Ncols) continue;
        const float bv = bias[col];
        #pragma unroll
        for (int i = 0; i < 2; ++i)
            #pragma unroll
            for (int q = 0; q < 4; ++q) {
                const int row = rowBase + i * 16 + r4 + q;
                Out[(size_t)row * Ncols + col] = acc[i][j][q] + bv;
            }
    }
}

// ---------------------------------------------------------------------------
// phaseA: role-split GRU tiles (round-12, proven).
// ---------------------------------------------------------------------------
__global__ __launch_bounds__(256) void phaseA(
    const short* __restrict__ ep, const short* __restrict__ er,
    const short* __restrict__ enc_wih, const float* __restrict__ enc_bih,
    const short* __restrict__ enc_whh, const float* __restrict__ enc_bhh,
    const short* __restrict__ rel_wih, const float* __restrict__ rel_bih,
    const short* __restrict__ rel_whh, const float* __restrict__ rel_bhh,
    const short* __restrict__ dec_wih, const float* __restrict__ dec_bih,
    const short* __restrict__ dec_whh, const float* __restrict__ dec_bhh,
    const float* __restrict__ hc, const short* __restrict__ hbc,
    float* __restrict__ hn, short* __restrict__ hbn,
    const float* __restrict__ hrc, const short* __restrict__ hrbc,
    float* __restrict__ hrn, short* __restrict__ hrbn,
    const short* __restrict__ hfbc, short* __restrict__ hfbn,
    const short* __restrict__ reads_b,
    int decBlocks, int encBlocks)
{
    __shared__ float xch[2][64][49];
    const int bid = blockIdx.x;
    const int wv = threadIdx.x >> 6;
    const int lane = threadIdx.x & 63;
    const int pair = wv >> 1, role = wv & 1;
    float* xchLane = &xch[pair][lane][0];

    if (bid < decBlocks) {
        const int tile = bid * 2 + pair;
        gru_tile_split(role, xchLane,
                       hbc, 256, reads_b, 128, dec_wih, 384, dec_bih,
                       hfbc, dec_whh, dec_bhh, nullptr, nullptr, hfbn, D_,
                       (tile / 12) * 32, (tile % 12) * 32, lane);
    } else if (bid < decBlocks + encBlocks) {
        const int tile = (bid - decBlocks) * 2 + pair;
        gru_tile_split(role, xchLane,
                       ep, 16, reads_b, 128, enc_wih, 160, enc_bih,
                       hbc, enc_whh, enc_bhh, hc, hn, hbn, C_,
                       (tile >> 3) * 32, (tile & 7) * 32, lane);
    } else {
        const int tile = (bid - decBlocks - encBlocks) * 2 + pair;
        gru_tile_split(role, xchLane,
                       er, 16, nullptr, 0, rel_wih, 32, rel_bih,
                       hrbc, rel_whh, rel_bhh, hrc, hrn, hrbn, C_,
                       (tile >> 3) * 32, (tile & 7) * 32, lane);
    }
}

// ---------------------------------------------------------------------------
// phaseHeads: wp GEMM (416 tiles) | rp GEMM (672 tiles) | out(t-1) from bf16 hf.
// ---------------------------------------------------------------------------
__global__ __launch_bounds__(256) void phaseHeads(
    const short* __restrict__ hbn, const short* __restrict__ write_w_b,
    const float* __restrict__ write_b, float* __restrict__ wp,
    const short* __restrict__ hrbn, const short* __restrict__ read_w_b,
    const float* __restrict__ read_b, float* __restrict__ rp,
    const short* __restrict__ hfbn, const float* __restrict__ out_w,
    const float* __restrict__ out_b, float* __restrict__ predrel,
    int outT, int wpBlocks, int rpBlocks)
{
    const int bid = blockIdx.x;
    const int wave = threadIdx.x >> 6;
    const int lane = threadIdx.x & 63;

    if (bid < wpBlocks) {
        const int tile = bid * 4 + wave;                 // 416: 32 rowT x 13 colT
        gemm_tile(hbn, write_w_b, write_b, wp, 385, C_,
                  (tile & 31) * 32, (tile >> 5) * 32, lane);
    } else if (bid < wpBlocks + rpBlocks) {
        const int tile = (bid - wpBlocks) * 4 + wave;    // 672: 32 rowT x 21 colT
        gemm_tile(hrbn, read_w_b, read_b, rp, 645, C_,
                  (tile & 31) * 32, (tile >> 5) * 32, lane);
    } else {
        const int widx = (bid - wpBlocks - rpBlocks) * 4 + wave;
        const int g = lane >> 3, li = lane & 7;
        const int row = widx * 8 + g;                    // < 5120
        const short* hrow = hfbn + (size_t)row * D_;
        float a0 = 0.f, a1 = 0.f;
        #pragma unroll
        for (int u = 0; u < 6; ++u) {
            const int k0 = u * 64 + li * 8;
            const bf16x8 v = *(const bf16x8*)(hrow + k0);
            #pragma unroll
            for (int r = 0; r < 8; ++r) {
                const float f = bf2f(v[r]);
                a0 = fmaf(f, out_w[k0 + r], a0);
                a1 = fmaf(f, out_w[D_ + k0 + r], a1);
            }
        }
        a0 += __shfl_xor(a0, 1); a0 += __shfl_xor(a0, 2); a0 += __shfl_xor(a0, 4);
        a1 += __shfl_xor(a1, 1); a1 += __shfl_xor(a1, 2); a1 += __shfl_xor(a1, 4);
        if (li == 0) {
            const int hh = row >> 10, aa = row & 1023;
            float* o = predrel + (((size_t)aa * H_ + hh) * TFUT_ + outT) * 2;
            o[0] = a0 + out_b[0];
            o[1] = a1 + out_b[1];
        }
    }
}

// ---------------------------------------------------------------------------
// NTM write: round-12 block-per-agent structure, hi/lo-only memory.
// ---------------------------------------------------------------------------
__global__ __launch_bounds__(256) void write_mem_k(const float* __restrict__ wp,
                                                   short* __restrict__ memhi, short* __restrict__ memlo,
                                                   float* __restrict__ normsG)
{
    const int a = blockIdx.x;
    const int b = a >> 4, p = a & 15;
    __shared__ float kw[128], er[128], ad[128], red[256], ww[16], logit[16];
    __shared__ float buf[2048];
    __shared__ float beta_s, knorm_s;
    const int tid = threadIdx.x;
    const float* w = wp + (size_t)a * 385;
    if (tid < 128) {
        kw[tid] = tanhf(w[tid]);
        er[tid] = sigmoidf_(w[129 + tid]);
        ad[tid] = tanhf(w[257 + tid]);
    }
    if (tid == 0) beta_s = softplusf_(w[128]);
    __syncthreads();

    red[tid] = (tid < 128) ? kw[tid] * kw[tid] : 0.f;
    __syncthreads();
    for (int s = 128; s > 0; s >>= 1) { if (tid < s) red[tid] += red[tid + s]; __syncthreads(); }
    if (tid == 0) knorm_s = sqrtf(red[0]) + 1e-16f;
    __syncthreads();

    const int s = tid >> 4, j = tid & 15;
    float dot = 0.f, ss = 0.f;
    {
        const size_t row = (size_t)(b * N_) + p * 16 + s;
        const short* hi = memhi + row * M_;
        const short* lo = memlo + row * M_;
        for (int k = j; k < 128; k += 16) {
            const float v = bf2f(hi[k]) + bf2f(lo[k]);
            dot += kw[k] * v; ss += v * v;
        }
    }
    red[tid] = dot; __syncthreads();
    for (int st = 8; st > 0; st >>= 1) { if (j < st) red[tid] += red[tid + st]; __syncthreads(); }
    float dotf = red[s * 16];
    __syncthreads();
    red[tid] = ss; __syncthreads();
    for (int st = 8; st > 0; st >>= 1) { if (j < st) red[tid] += red[tid + st]; __syncthreads(); }
    float ssf = red[s * 16];
    if (j == 0) {
        float mn = sqrtf(ssf) + 1e-16f;
        logit[s] = beta_s * (dotf / (mn * knorm_s));
    }
    __syncthreads();
    if (tid == 0) {
        float mx = -1e30f;
        for (int i = 0; i < 16; ++i) mx = fmaxf(mx, logit[i]);
        float sum = 0.f;
        for (int i = 0; i < 16; ++i) { float e = __expf(logit[i] - mx); ww[i] = e; sum += e; }
        float inv = 1.f / sum;
        for (int i = 0; i < 16; ++i) ww[i] *= inv;
    }
    __syncthreads();
    for (int idx = tid; idx < 16 * 128; idx += 256) {
        int si = idx >> 7, m = idx & 127;
        size_t g = ((size_t)(b * N_) + p * 16 + si) * M_ + m;
        float wwv = ww[si];
        const float old = bf2f(memhi[g]) + bf2f(memlo[g]);
        float v = old * (1.f - wwv * er[m]) + wwv * ad[m];
        const short hv = (short)f2bf(v);
        memhi[g] = hv;
        memlo[g] = (short)f2bf(v - bf2f(hv));
        buf[idx] = v;
    }
    __syncthreads();
    {
        float ssq = 0.f;
        #pragma unroll
        for (int i = 0; i < 8; ++i) { float v = buf[s * 128 + j + 16 * i]; ssq += v * v; }
        #pragma unroll
        for (int m = 1; m < 16; m <<= 1) ssq += __shfl_xor(ssq, m);
        if (j == 0) normsG[b * N_ + p * 16 + s] = sqrtf(ssq) + 1e-16f;
    }
}

// ---------------------------------------------------------------------------
// NTM read (sims from hi/lo; PV reconstructs hi+lo) — round-13 body, proven.
// ---------------------------------------------------------------------------
__global__ __launch_bounds__(256) void read_k2(const float* __restrict__ rp,
                                               const short* __restrict__ memhi,
                                               const short* __restrict__ memlo,
                                               const float* __restrict__ normsG,
                                               short* __restrict__ reads_b)
{
    const int b = blockIdx.x;
    const int h = blockIdx.y;
    __shared__ __align__(16) float kq[16 * 132];
    __shared__ float S[16 * 260];
    __shared__ float beta_s[16], knorm_s[16], inv_s[16];
    const int t = threadIdx.x;
    const int a = t >> 4;
    const int sub = t & 15;

    {
        const float* base = rp + ((size_t)(b * 16 + a)) * 645 + h * 129;
        const int k0 = sub * 8;
        float v[8]; float ss = 0.f;
        #pragma unroll
        for (int r = 0; r < 8; ++r) { v[r] = tanhf(base[k0 + r]); ss += v[r] * v[r]; }
        float* dst = kq + a * 132 + k0;
        *(float4*)dst = make_float4(v[0], v[1], v[2], v[3]);
        *(float4*)(dst + 4) = make_float4(v[4], v[5], v[6], v[7]);
        #pragma unroll
        for (int m = 1; m < 16; m <<= 1) ss += __shfl_xor(ss, m);
        if (sub == 0) {
            knorm_s[a] = sqrtf(ss) + 1e-16f;
            beta_s[a] = softplusf_(base[128]);
        }
    }
    __syncthreads();

    {
        const int wave = t >> 6, lane = t & 63;
        const int l16 = lane & 15, kb8 = (lane >> 4) * 8;
        const int slotBase = wave * 64;
        const f32x4 z4 = {0.f, 0.f, 0.f, 0.f};
        f32x4 acc[4] = {z4, z4, z4, z4};
        const short* mbh = memhi + (size_t)b * N_ * M_;
        const short* mbl = memlo + (size_t)b * N_ * M_;
        #pragma unroll
        for (int kc = 0; kc < 128; kc += 32) {
            const float* ap = kq + l16 * 132 + kc + kb8;
            bf16x8 ah, al;
            #pragma unroll
            for (int r = 0; r < 8; ++r) {
                const float av = ap[r];
                const short hv = (short)f2bf(av);
                ah[r] = hv; al[r] = (short)f2bf(av - bf2f(hv));
            }
            #pragma unroll
            for (int tt = 0; tt < 4; ++tt) {
                const size_t roff = (size_t)(slotBase + tt * 16 + l16) * M_ + kc + kb8;
                const bf16x8 bh = *(const bf16x8*)(mbh + roff);
                const bf16x8 bl = *(const bf16x8*)(mbl + roff);
                acc[tt] = __builtin_amdgcn_mfma_f32_16x16x32_bf16(ah, bh, acc[tt], 0, 0, 0);
                acc[tt] = __builtin_amdgcn_mfma_f32_16x16x32_bf16(ah, bl, acc[tt], 0, 0, 0);
                acc[tt] = __builtin_amdgcn_mfma_f32_16x16x32_bf16(al, bh, acc[tt], 0, 0, 0);
            }
        }
        const int r4 = (lane >> 4) * 4;
        #pragma unroll
        for (int tt = 0; tt < 4; ++tt) {
            const int slot = slotBase + tt * 16 + l16;
            const float nv = normsG[b * N_ + slot];
            #pragma unroll
            for (int q = 0; q < 4; ++q) {
                const int aq = r4 + q;
                const float lg = ((slot >> 4) == aq) ? -1e30f
                               : beta_s[aq] * acc[tt][q] / (nv * knorm_s[aq]);
                S[aq * 260 + slot] = lg;
            }
        }
    }
    __syncthreads();

    {
        float mx = -1e30f;
        #pragma unroll
        for (int i = 0; i < 16; ++i) mx = fmaxf(mx, S[a * 260 + sub + 16 * i]);
        #pragma unroll
        for (int m = 1; m < 16; m <<= 1) mx = fmaxf(mx, __shfl_xor(mx, m));
        float e[16]; float sum = 0.f;
        #pragma unroll
        for (int i = 0; i < 16; ++i) { e[i] = __expf(S[a * 260 + sub + 16 * i] - mx); sum += e[i]; }
        #pragma unroll
        for (int i = 0; i < 16; ++i) S[a * 260 + sub + 16 * i] = e[i];
        #pragma unroll
        for (int m = 1; m < 16; m <<= 1) sum += __shfl_xor(sum, m);
        if (sub == 0) inv_s[a] = 1.f / sum;
    }
    __syncthreads();

    {
        const int m0 = sub * 8;
        const short* mbh = memhi + (size_t)b * N_ * M_ + m0;
        const short* mbl = memlo + (size_t)b * N_ * M_ + m0;
        float acc[8];
        #pragma unroll
        for (int r = 0; r < 8; ++r) acc[r] = 0.f;
        const float* Sa = S + a * 260;
        #pragma unroll 2
        for (int n = 0; n < N_; ++n) {
            const float w = Sa[n];
            const bf16x8 vh = *(const bf16x8*)(mbh + (size_t)n * M_);
            const bf16x8 vl = *(const bf16x8*)(mbl + (size_t)n * M_);
            #pragma unroll
            for (int r = 0; r < 8; ++r)
                acc[r] = fmaf(w, bf2f(vh[r]) + bf2f(vl[r]), acc[r]);
        }
        const float inv = inv_s[a];
        short pk[8];
        #pragma unroll
        for (int r = 0; r < 8; ++r) pk[r] = (short)f2bf(acc[r] * inv);
        *(bf16x8*)(reads_b + ((size_t)h * A_ + b * 16 + a) * M_ + m0) = *(bf16x8*)pk;
    }
}

__global__ __launch_bounds__(256) void cumsum_k(const float* __restrict__ past,
                                                const float* __restrict__ predrel,
                                                float* __restrict__ pred)
{
    const int idx = blockIdx.x * 256 + threadIdx.x;
    if (idx >= A_ * H_ * 2) return;
    const int c = idx & 1;
    const int ah = idx >> 1;
    const int a = ah / H_;
    float acc = past[((size_t)a * TPAST_ + TPAST_ - 1) * 2 + c];
    const float* pr = predrel + (size_t)ah * TFUT_ * 2 + c;
    float* pd = pred + (size_t)ah * TFUT_ * 2 + c;
    for (int t = 0; t < TFUT_; ++t) { acc += pr[t * 2]; pd[t * 2] = acc; }
}

extern "C" void kernel_launch(void* const* d_in, const int* in_sizes, int n_in,
                              void* d_out, int out_size, void* d_ws, size_t ws_size,
                              hipStream_t stream)
{
    const float* past       = (const float*)d_in[0];
    const float* past_rel   = (const float*)d_in[1];
    const float* ep_w1      = (const float*)d_in[2];
    const float* ep_b1      = (const float*)d_in[3];
    const float* ep_w2      = (const float*)d_in[4];
    const float* ep_b2      = (const float*)d_in[5];
    const float* er_w1      = (const float*)d_in[6];
    const float* er_b1      = (const float*)d_in[7];
    const float* er_w2      = (const float*)d_in[8];
    const float* er_b2      = (const float*)d_in[9];
    const float* enc_wih    = (const float*)d_in[10];
    const float* enc_whh    = (const float*)d_in[11];
    const float* enc_bih    = (const float*)d_in[12];
    const float* enc_bhh    = (const float*)d_in[13];
    const float* rel_wih    = (const float*)d_in[14];
    const float* rel_whh    = (const float*)d_in[15];
    const float* rel_bih    = (const float*)d_in[16];
    const float* rel_bhh    = (const float*)d_in[17];
    const float* dec_wih    = (const float*)d_in[18];
    const float* dec_whh    = (const float*)d_in[19];
    const float* dec_bih    = (const float*)d_in[20];
    const float* dec_bhh    = (const float*)d_in[21];
    const float* out_w      = (const float*)d_in[22];
    const float* out_b      = (const float*)d_in[23];
    const float* read_w     = (const float*)d_in[24];
    const float* read_b     = (const float*)d_in[25];
    const float* write_w    = (const float*)d_in[26];
    const float* write_b    = (const float*)d_in[27];
    const float* init_r     = (const float*)d_in[28];
    const float* h_bias     = (const float*)d_in[29];
    const float* h_rel_bias = (const float*)d_in[30];
    const float* h_fut_bias = (const float*)d_in[31];
    const float* mem_bias   = (const float*)d_in[32];

    float* pred    = (float*)d_out;
    float* predrel = pred + (size_t)A_ * H_ * TFUT_ * 2;

    float* ws = (float*)d_ws;
    size_t off = 0;
    auto alloc = [&](size_t n) { float* p = ws + off; off += n; return p; };
    float* h0     = alloc((size_t)A_ * C_);
    float* h1     = alloc((size_t)A_ * C_);
    float* hr0    = alloc((size_t)A_ * C_);
    float* hr1    = alloc((size_t)A_ * C_);
    float* wp     = alloc((size_t)A_ * 385);
    float* rp     = alloc((size_t)A_ * 645);
    float* normsG = alloc((size_t)B_ * N_);

    short* sws = (short*)(ws + off);
    size_t soff = 0;
    auto salloc = [&](size_t n) { short* p = sws + soff; soff += n; return p; };
    short* emb_p_b   = salloc((size_t)TPAST_ * A_ * EMB_);
    short* emb_r_b   = salloc((size_t)TPAST_ * A_ * EMB_);
    short* hb0       = salloc((size_t)A_ * C_);
    short* hb1       = salloc((size_t)A_ * C_);
    short* hrb0      = salloc((size_t)A_ * C_);
    short* hrb1      = salloc((size_t)A_ * C_);
    short* hfb0      = salloc((size_t)H_ * A_ * D_);
    short* hfb1      = salloc((size_t)H_ * A_ * D_);
    short* reads_b   = salloc((size_t)H_ * A_ * M_);
    short* memhi     = salloc((size_t)B_ * N_ * M_);
    short* memlo     = salloc((size_t)B_ * N_ * M_);
    short* enc_wih_b = salloc((size_t)768 * 160);
    short* enc_whh_b = salloc((size_t)768 * 256);
    short* rel_wih_b = salloc((size_t)768 * 32);
    short* rel_whh_b = salloc((size_t)768 * 256);
    short* dec_wih_b = salloc((size_t)1152 * 384);
    short* dec_whh_b = salloc((size_t)1152 * 384);
    short* write_w_b = salloc((size_t)416 * 256);
    short* read_w_b  = salloc((size_t)672 * 256);
    (void)ws_size; (void)in_sizes; (void)n_in; (void)out_size;

    Cvt8 cp;
    cp.c[0] = {enc_wih, enc_wih_b, 768, 144, 160, 768 * 160};
    cp.c[1] = {enc_whh, enc_whh_b, 768, 256, 256, 768 * 256};
    cp.c[2] = {rel_wih, rel_wih_b, 768, 16, 32, 768 * 32};
    cp.c[3] = {rel_whh, rel_whh_b, 768, 256, 256, 768 * 256};
    cp.c[4] = {dec_wih, dec_wih_b, 1152, 384, 384, 1152 * 384};
    cp.c[5] = {dec_whh, dec_whh_b, 1152, 384, 384, 1152 * 384};
    cp.c[6] = {write_w, write_w_b, 385, 256, 256, 416 * 256};
    cp.c[7] = {read_w, read_w_b, 645, 256, 256, 672 * 256};
    convert_all<<<1024, 256, 0, stream>>>(cp);

    init_k<<<(B_ * N_ * M_ + 255) / 256, 256, 0, stream>>>(
        h0, h_bias, hb0, hr0, h_rel_bias, hrb0, h_fut_bias, hfb0,
        reads_b, init_r, memhi, memlo, normsG, mem_bias);
    embed2_k<<<(2 * A_ * TPAST_ + 255) / 256, 256, 0, stream>>>(
        past, past_rel, ep_w1, ep_b1, ep_w2, ep_b2, er_w1, er_b1, er_w2, er_b2,
        emb_p_b, emb_r_b);

    float *hc = h0, *hn = h1, *hrc = hr0, *hrn = hr1;
    short *hbc = hb0, *hbn = hb1, *hrbc = hrb0, *hrbn = hrb1, *hfbc = hfb0, *hfbn = hfb1;

    const dim3 g_read(B_, H_);   // (64, 5)

    for (int t = 0; t < TTOT_; ++t) {
        const short* ep = (t < TPAST_) ? emb_p_b + (size_t)t * A_ * EMB_ : nullptr;
        const short* er = (t < TPAST_) ? emb_r_b + (size_t)t * A_ * EMB_ : nullptr;

        // phase A: dec(t-1) [t>=1] + enc(t) + rel(t)
        const int decBlocks = (t == 0) ? 0 : 960;
        phaseA<<<decBlocks + 256, 256, 0, stream>>>(
            ep, er,
            enc_wih_b, enc_bih, enc_whh_b, enc_bhh,
            rel_wih_b, rel_bih, rel_whh_b, rel_bhh,
            dec_wih_b, dec_bih, dec_whh_b, dec_bhh,
            hc, hbc, hn, hbn,
            hrc, hrbc, hrn, hrbn,
            hfbc, hfbn,
            reads_b, decBlocks, 128);

        // phase Heads: wp GEMM + rp GEMM (+ out(t-1) when t>=21)
        const int gridH = (t >= 21) ? 432 : 272;
        phaseHeads<<<gridH, 256, 0, stream>>>(
            hbn, write_w_b, write_b, wp,
            hrbn, read_w_b, read_b, rp,
            hfbn, out_w, out_b, predrel, t - 21, 104, 168);

        // memory write (hi/lo only)
        write_mem_k<<<A_, 256, 0, stream>>>(wp, memhi, memlo, normsG);

        // memory read -> reads_b(t)
        read_k2<<<g_read, 256, 0, stream>>>(rp, memhi, memlo, normsG, reads_b);

        // swaps
        float* tf; short* ts;
        tf = hc; hc = hn; hn = tf;       ts = hbc; hbc = hbn; hbn = ts;
        tf = hrc; hrc = hrn; hrn = tf;   ts = hrbc; hrbc = hrbn; hrbn = ts;
        if (t >= 1) {
            ts = hfbc; hfbc = hfbn; hfbn = ts;
        }
    }

    // epilogue: dec(49), out(49), cumsum
    phaseA<<<960, 256, 0, stream>>>(
        nullptr, nullptr,
        enc_wih_b, enc_bih, enc_whh_b, enc_bhh,
        rel_wih_b, rel_bih, rel_whh_b, rel_bhh,
        dec_wih_b, dec_bih, dec_whh_b, dec_bhh,
        hc, hbc, hn, hbn,
        hrc, hrbc, hrn, hrbn,
        hfbc, hfbn,
        reads_b, 960, 0);
    phaseHeads<<<160, 256, 0, stream>>>(
        hbn, write_w_b, write_b, wp,
        hrbn, read_w_b, read_b, rp,
        hfbn, out_w, out_b, predrel, TFUT_ - 1, 0, 0);
    cumsum_k<<<(A_ * H_ * 2 + 255) / 256, 256, 0, stream>>>(past, predrel, pred);
}